// Round 1
// baseline (7902.353 us; speedup 1.0000x reference)
//
#include <hip/hip_runtime.h>
#include <cstdint>
#include <cstddef>

// ---------------------------------------------------------------------------
// BasicVQVAE forward, fp32 baseline (round 1 = correctness anchor).
// B=8192, X=4096, H=4096, Z=512, E=512, K_codes=8192.
// All GEMMs on the vector ALU (no fp32 MFMA on CDNA4).
// ---------------------------------------------------------------------------

#define BM 128
#define BN 128
#define BKT 16
#define LDA 132   // BM + 4 pad: transposed-store bank conflicts -> 2-way (free)
#define LDB 132

// C[M,N] = act(A[M,K] @ B[K,N] + bias[N]); optional A-row indirection (gather).
__global__ __launch_bounds__(256, 2)
void gemm_bias_act(const float* __restrict__ A, const float* __restrict__ B,
                   const float* __restrict__ bias, float* __restrict__ C,
                   int M, int N, int K, int relu, const int* __restrict__ rowidx)
{
    __shared__ float as[BKT][LDA];   // as[k][m]
    __shared__ float bs[BKT][LDB];   // bs[k][n]
    const int tid = threadIdx.x;
    const int tx = tid & 15;         // col group
    const int ty = tid >> 4;         // row group
    const int row0 = blockIdx.y * BM;
    const int col0 = blockIdx.x * BN;

    // A-tile loader: 128 rows x 16 cols, 2 float4 per thread
    const int ar = tid >> 2;             // 0..63
    const int ac = (tid & 3) << 2;       // 0,4,8,12
    // B-tile loader: 16 rows x 128 cols, 2 float4 per thread
    const int br = tid >> 5;             // 0..7
    const int bc = (tid & 31) << 2;      // 0..124

    int arow0 = row0 + ar;
    int arow1 = row0 + ar + 64;
    if (rowidx) { arow0 = rowidx[arow0]; arow1 = rowidx[arow1]; }
    const float* Ap0 = A + (size_t)arow0 * K + ac;
    const float* Ap1 = A + (size_t)arow1 * K + ac;
    const float* Bp0 = B + (size_t)br * N + col0 + bc;
    const float* Bp1 = B + (size_t)(br + 8) * N + col0 + bc;

    float acc[8][8];
#pragma unroll
    for (int i = 0; i < 8; ++i)
#pragma unroll
        for (int j = 0; j < 8; ++j) acc[i][j] = 0.f;

    for (int k0 = 0; k0 < K; k0 += BKT) {
        float4 a0 = *(const float4*)(Ap0 + k0);
        float4 a1 = *(const float4*)(Ap1 + k0);
        float4 b0 = *(const float4*)(Bp0 + (size_t)k0 * N);
        float4 b1 = *(const float4*)(Bp1 + (size_t)k0 * N);
        __syncthreads();
        as[ac + 0][ar] = a0.x; as[ac + 1][ar] = a0.y;
        as[ac + 2][ar] = a0.z; as[ac + 3][ar] = a0.w;
        as[ac + 0][ar + 64] = a1.x; as[ac + 1][ar + 64] = a1.y;
        as[ac + 2][ar + 64] = a1.z; as[ac + 3][ar + 64] = a1.w;
        *(float4*)&bs[br][bc] = b0;
        *(float4*)&bs[br + 8][bc] = b1;
        __syncthreads();
#pragma unroll
        for (int k = 0; k < BKT; ++k) {
            float af[8], bf[8];
            *(float4*)&af[0] = *(const float4*)&as[k][ty * 8];
            *(float4*)&af[4] = *(const float4*)&as[k][ty * 8 + 4];
            *(float4*)&bf[0] = *(const float4*)&bs[k][tx * 8];
            *(float4*)&bf[4] = *(const float4*)&bs[k][tx * 8 + 4];
#pragma unroll
            for (int i = 0; i < 8; ++i)
#pragma unroll
                for (int j = 0; j < 8; ++j)
                    acc[i][j] = fmaf(af[i], bf[j], acc[i][j]);
        }
    }

    float bv[8];
#pragma unroll
    for (int j = 0; j < 8; ++j) bv[j] = bias[col0 + tx * 8 + j];
#pragma unroll
    for (int i = 0; i < 8; ++i) {
        const int row = row0 + ty * 8 + i;
        float* Cp = C + (size_t)row * N + col0 + tx * 8;
        float4 o0, o1;
        o0.x = acc[i][0] + bv[0]; o0.y = acc[i][1] + bv[1];
        o0.z = acc[i][2] + bv[2]; o0.w = acc[i][3] + bv[3];
        o1.x = acc[i][4] + bv[4]; o1.y = acc[i][5] + bv[5];
        o1.z = acc[i][6] + bv[6]; o1.w = acc[i][7] + bv[7];
        if (relu) {
            o0.x = fmaxf(o0.x, 0.f); o0.y = fmaxf(o0.y, 0.f);
            o0.z = fmaxf(o0.z, 0.f); o0.w = fmaxf(o0.w, 0.f);
            o1.x = fmaxf(o1.x, 0.f); o1.y = fmaxf(o1.y, 0.f);
            o1.z = fmaxf(o1.z, 0.f); o1.w = fmaxf(o1.w, 0.f);
        }
        *(float4*)(Cp) = o0;
        *(float4*)(Cp + 4) = o1;
    }
}

// per-code squared norms ||c_j||^2, one wave per code
__global__ void cnorm_kernel(const float* __restrict__ CB, float* __restrict__ cnorm, int E)
{
    const int j = blockIdx.x;
    const float* c = CB + (size_t)j * E;
    float s = 0.f;
    for (int e = threadIdx.x; e < E; e += 64) { float v = c[e]; s += v * v; }
#pragma unroll
    for (int off = 32; off; off >>= 1) s += __shfl_down(s, off);
    if (threadIdx.x == 0) cnorm[j] = s;
}

// scores[m][j] = ||c_j||^2 - 2 * ze_m . c_j ; fused per-row min over the 128-code
// block tile, partials to (partv, parti); first-occurrence tie-break.
__global__ __launch_bounds__(256, 2)
void dist_argmin(const float* __restrict__ ZE, const float* __restrict__ CB,
                 const float* __restrict__ cnorm, float* __restrict__ partv,
                 int* __restrict__ parti, int K)
{
    __shared__ float as[BKT][LDA];   // as[k][m]  (z_e rows)
    __shared__ float bs[BKT][LDB];   // bs[k][n]  (codes, transposed)
    const int tid = threadIdx.x;
    const int tx = tid & 15;
    const int ty = tid >> 4;
    const int row0 = blockIdx.y * BM;
    const int col0 = blockIdx.x * BN;

    const int ar = tid >> 2;
    const int ac = (tid & 3) << 2;
    const float* Ap0 = ZE + (size_t)(row0 + ar) * K + ac;
    const float* Ap1 = ZE + (size_t)(row0 + ar + 64) * K + ac;
    const float* Cp0 = CB + (size_t)(col0 + ar) * K + ac;
    const float* Cp1 = CB + (size_t)(col0 + ar + 64) * K + ac;

    float acc[8][8];
#pragma unroll
    for (int i = 0; i < 8; ++i)
#pragma unroll
        for (int j = 0; j < 8; ++j) acc[i][j] = 0.f;

    for (int k0 = 0; k0 < K; k0 += BKT) {
        float4 a0 = *(const float4*)(Ap0 + k0);
        float4 a1 = *(const float4*)(Ap1 + k0);
        float4 b0 = *(const float4*)(Cp0 + k0);
        float4 b1 = *(const float4*)(Cp1 + k0);
        __syncthreads();
        as[ac + 0][ar] = a0.x; as[ac + 1][ar] = a0.y;
        as[ac + 2][ar] = a0.z; as[ac + 3][ar] = a0.w;
        as[ac + 0][ar + 64] = a1.x; as[ac + 1][ar + 64] = a1.y;
        as[ac + 2][ar + 64] = a1.z; as[ac + 3][ar + 64] = a1.w;
        bs[ac + 0][ar] = b0.x; bs[ac + 1][ar] = b0.y;
        bs[ac + 2][ar] = b0.z; bs[ac + 3][ar] = b0.w;
        bs[ac + 0][ar + 64] = b1.x; bs[ac + 1][ar + 64] = b1.y;
        bs[ac + 2][ar + 64] = b1.z; bs[ac + 3][ar + 64] = b1.w;
        __syncthreads();
#pragma unroll
        for (int k = 0; k < BKT; ++k) {
            float af[8], bf[8];
            *(float4*)&af[0] = *(const float4*)&as[k][ty * 8];
            *(float4*)&af[4] = *(const float4*)&as[k][ty * 8 + 4];
            *(float4*)&bf[0] = *(const float4*)&bs[k][tx * 8];
            *(float4*)&bf[4] = *(const float4*)&bs[k][tx * 8 + 4];
#pragma unroll
            for (int i = 0; i < 8; ++i)
#pragma unroll
                for (int j = 0; j < 8; ++j)
                    acc[i][j] = fmaf(af[i], bf[j], acc[i][j]);
        }
    }

    float cn8[8];
#pragma unroll
    for (int j = 0; j < 8; ++j) cn8[j] = cnorm[col0 + tx * 8 + j];

    float bvv[8]; int bii[8];
#pragma unroll
    for (int i = 0; i < 8; ++i) {
        bvv[i] = __builtin_inff(); bii[i] = 0;
#pragma unroll
        for (int j = 0; j < 8; ++j) {   // ascending col: first-min kept
            float v = cn8[j] - 2.f * acc[i][j];
            if (v < bvv[i]) { bvv[i] = v; bii[i] = col0 + tx * 8 + j; }
        }
    }
    __syncthreads();                    // done with as/bs; alias for reduction
    float* rv = (float*)as;             // [128][16] floats (2048 <= 16*132)
    int*   ri = (int*)bs;
#pragma unroll
    for (int i = 0; i < 8; ++i) {
        rv[(ty * 8 + i) * 16 + tx] = bvv[i];
        ri[(ty * 8 + i) * 16 + tx] = bii[i];
    }
    __syncthreads();
    if (tid < 128) {
        float best = rv[tid * 16]; int bi = ri[tid * 16];
#pragma unroll
        for (int t = 1; t < 16; ++t) {  // ascending tx = ascending cols
            float v = rv[tid * 16 + t]; int ii = ri[tid * 16 + t];
            if (v < best || (v == best && ii < bi)) { best = v; bi = ii; }
        }
        const int m = row0 + tid;
        partv[(size_t)m * gridDim.x + blockIdx.x] = best;
        parti[(size_t)m * gridDim.x + blockIdx.x] = bi;
    }
}

__global__ void argmin_reduce(const float* __restrict__ partv, const int* __restrict__ parti,
                              int* __restrict__ idx, int M, int P)
{
    const int m = blockIdx.x * blockDim.x + threadIdx.x;
    if (m >= M) return;
    const float* pv = partv + (size_t)m * P;
    const int* pi = parti + (size_t)m * P;
    float best = pv[0]; int bi = pi[0];
    for (int t = 1; t < P; ++t) {       // ascending block = ascending cols
        float v = pv[t]; int ii = pi[t];
        if (v < best || (v == best && ii < bi)) { best = v; bi = ii; }
    }
    idx[m] = bi;
}

// per-sample: sum (c[idx] - z_e)^2 -> atomic accum; histogram count
__global__ __launch_bounds__(256)
void vq_stats(const float* __restrict__ ZE, const float* __restrict__ CB,
              const int* __restrict__ idx, int* __restrict__ counts,
              float* __restrict__ vqaccum, int E)
{
    const int i = blockIdx.x;
    const int id = idx[i];
    const float* c = CB + (size_t)id * E;
    const float* z = ZE + (size_t)i * E;
    float s = 0.f;
    for (int e = threadIdx.x; e < E; e += 256) { float d = c[e] - z[e]; s += d * d; }
#pragma unroll
    for (int off = 32; off; off >>= 1) s += __shfl_down(s, off);
    __shared__ float red[4];
    const int lane = threadIdx.x & 63, w = threadIdx.x >> 6;
    if (lane == 0) red[w] = s;
    __syncthreads();
    if (threadIdx.x == 0) {
        atomicAdd(vqaccum, red[0] + red[1] + red[2] + red[3]);
        atomicAdd(counts + id, 1);
    }
}

__global__ void zero_kernel(int* __restrict__ p, int n)
{
    const int i = blockIdx.x * 256 + threadIdx.x;
    if (i < n) p[i] = 0;
}

__global__ __launch_bounds__(256)
void finalize(const int* __restrict__ counts, const float* __restrict__ vqaccum,
              float* __restrict__ tail, int NCODE, float invB, float scale)
{
    float s = 0.f;
    for (int j = threadIdx.x; j < NCODE; j += 256) {
        float p = (float)counts[j] * invB;
        s += p * logf(p + 1e-10f);
    }
#pragma unroll
    for (int off = 32; off; off >>= 1) s += __shfl_down(s, off);
    __shared__ float red[4];
    const int lane = threadIdx.x & 63, w = threadIdx.x >> 6;
    if (lane == 0) red[w] = s;
    __syncthreads();
    if (threadIdx.x == 0) {
        tail[0] = vqaccum[0] * scale;            // vq_loss = 1.25 * mean
        tail[1] = expf(-(red[0] + red[1] + red[2] + red[3]));  // perplexity
    }
}

extern "C" void kernel_launch(void* const* d_in, const int* in_sizes, int n_in,
                              void* d_out, int out_size, void* d_ws, size_t ws_size,
                              hipStream_t stream)
{
    const float* x      = (const float*)d_in[0];
    const float* enc_w1 = (const float*)d_in[1];
    const float* enc_b1 = (const float*)d_in[2];
    const float* enc_w2 = (const float*)d_in[3];
    const float* enc_b2 = (const float*)d_in[4];
    const float* pre_w  = (const float*)d_in[5];
    const float* pre_b  = (const float*)d_in[6];
    const float* cb     = (const float*)d_in[7];
    const float* dec_w1 = (const float*)d_in[8];
    const float* dec_b1 = (const float*)d_in[9];
    const float* dec_w2 = (const float*)d_in[10];
    const float* dec_b2 = (const float*)d_in[11];
    float* out = (float*)d_out;

    const int B = 8192, X = 4096, H = 4096, Z = 512, E = 512, NC = 8192;

    char* w = (char*)d_ws;
    float* h_buf = (float*)(w);                       // B*H floats (reused for hd)
    float* z_buf = (float*)(w + 134217728);           // B*Z
    float* ze    = (float*)(w + 150994944);           // B*E
    float* cn    = (float*)(w + 167772160);           // NC
    float* pv    = (float*)(w + 167804928);           // B*64
    int*   pi    = (int*)  (w + 169902080);           // B*64
    int*   idx   = (int*)  (w + 171999232);           // B
    int*   cnt   = (int*)  (w + 172032000);           // NC
    float* vqa   = (float*)(w + 172064768);           // 1 (contiguous after cnt)

    dim3 blk(256);

    // zero counts + vq accumulator (ws is poisoned 0xAA before every launch)
    zero_kernel<<<(NC + 1 + 255) / 256, blk, 0, stream>>>(cnt, NC + 1);

    // h = relu(x @ enc_w1 + b1)
    gemm_bias_act<<<dim3(H / BN, B / BM), blk, 0, stream>>>(x, enc_w1, enc_b1, h_buf, B, H, X, 1, nullptr);
    // z = h @ enc_w2 + b2
    gemm_bias_act<<<dim3(Z / BN, B / BM), blk, 0, stream>>>(h_buf, enc_w2, enc_b2, z_buf, B, Z, H, 0, nullptr);
    // z_e = z @ pre_w + pre_b
    gemm_bias_act<<<dim3(E / BN, B / BM), blk, 0, stream>>>(z_buf, pre_w, pre_b, ze, B, E, Z, 0, nullptr);

    // VQ: argmin_j ||z_e - c_j||^2
    cnorm_kernel<<<NC, 64, 0, stream>>>(cb, cn, E);
    dist_argmin<<<dim3(NC / BN, B / BM), blk, 0, stream>>>(ze, cb, cn, pv, pi, E);
    argmin_reduce<<<B / 256, blk, 0, stream>>>(pv, pi, idx, B, NC / BN);
    vq_stats<<<B, blk, 0, stream>>>(ze, cb, idx, cnt, vqa, E);

    // decoder: forward z_st == z_q == codebook[idx] (straight-through)
    gemm_bias_act<<<dim3(H / BN, B / BM), blk, 0, stream>>>(cb, dec_w1, dec_b1, h_buf, B, H, E, 1, idx);
    gemm_bias_act<<<dim3(X / BN, B / BM), blk, 0, stream>>>(h_buf, dec_w2, dec_b2, out, B, X, H, 0, nullptr);

    // tail scalars: [vq_loss, perplexity]
    finalize<<<1, blk, 0, stream>>>(cnt, vqa, out + (out_size - 2), NC,
                                    1.f / (float)B, 1.25f / ((float)B * (float)E));
}

// Round 2
// 5389.957 us; speedup vs baseline: 1.4661x; 1.4661x over previous
//
#include <hip/hip_runtime.h>
#include <cstdint>
#include <cstddef>

// ---------------------------------------------------------------------------
// BasicVQVAE forward. Round 2:
//  - encoder + VQ distance stay fp32 (argmin exactness) with LDS bank-conflict
//    fix (4-col split microtile: tx*4 / 64+tx*4 -> 2-way aliasing = free)
//  - decoder (post-argmin, precision-tolerant) -> bf16 MFMA 16x16x32,
//    m97 structure: 128x128 tile, BK=32, global_load_lds width=16
// B=8192, X=4096, H=4096, Z=512, E=512, K_codes=8192.
// ---------------------------------------------------------------------------

#define BM 128
#define BN 128
#define BKT 16
#define LDA 132
#define LDB 132

__device__ __forceinline__ short f2bf(float v) {
    union { float f; unsigned u; } x; x.f = v;
    unsigned r = x.u + 0x7fff + ((x.u >> 16) & 1);   // round-to-nearest-even
    return (short)(r >> 16);
}

__device__ __forceinline__ void gload16(const void* g, void* l) {
    __builtin_amdgcn_global_load_lds(
        (const __attribute__((address_space(1))) void*)(uintptr_t)g,
        (__attribute__((address_space(3))) void*)(uintptr_t)l,
        16, 0, 0);
}

typedef __attribute__((ext_vector_type(8))) short bf16x8;
typedef __attribute__((ext_vector_type(4))) float floatx4;

// ============================ fp32 GEMM (encoder) ==========================
// C[M,N] = act(A[M,K] @ B[K,N] + bias[N])
__global__ __launch_bounds__(256, 2)
void gemm_bias_act(const float* __restrict__ A, const float* __restrict__ B,
                   const float* __restrict__ bias, float* __restrict__ C,
                   int M, int N, int K, int relu)
{
    __shared__ float as[BKT][LDA];   // as[k][m]
    __shared__ float bs[BKT][LDB];   // bs[k][n]
    const int tid = threadIdx.x;
    const int tx = tid & 15;
    const int ty = tid >> 4;
    const int row0 = blockIdx.y * BM;
    const int col0 = blockIdx.x * BN;

    const int ar = tid >> 2;             // 0..63
    const int ac = (tid & 3) << 2;       // 0,4,8,12
    const int br = tid >> 5;             // 0..7
    const int bc = (tid & 31) << 2;      // 0..124

    const float* Ap0 = A + (size_t)(row0 + ar) * K + ac;
    const float* Ap1 = A + (size_t)(row0 + ar + 64) * K + ac;
    const float* Bp0 = B + (size_t)br * N + col0 + bc;
    const float* Bp1 = B + (size_t)(br + 8) * N + col0 + bc;

    float acc[8][8];   // [row i][col j]; j 0..3 -> tx*4+j, j 4..7 -> 64+tx*4+(j-4)
#pragma unroll
    for (int i = 0; i < 8; ++i)
#pragma unroll
        for (int j = 0; j < 8; ++j) acc[i][j] = 0.f;

    for (int k0 = 0; k0 < K; k0 += BKT) {
        float4 a0 = *(const float4*)(Ap0 + k0);
        float4 a1 = *(const float4*)(Ap1 + k0);
        float4 b0 = *(const float4*)(Bp0 + (size_t)k0 * N);
        float4 b1 = *(const float4*)(Bp1 + (size_t)k0 * N);
        __syncthreads();
        as[ac + 0][ar] = a0.x; as[ac + 1][ar] = a0.y;
        as[ac + 2][ar] = a0.z; as[ac + 3][ar] = a0.w;
        as[ac + 0][ar + 64] = a1.x; as[ac + 1][ar + 64] = a1.y;
        as[ac + 2][ar + 64] = a1.z; as[ac + 3][ar + 64] = a1.w;
        *(float4*)&bs[br][bc] = b0;
        *(float4*)&bs[br + 8][bc] = b1;
        __syncthreads();
#pragma unroll
        for (int k = 0; k < BKT; ++k) {
            float af[8], bf0[4], bf1[4];
            *(float4*)&af[0] = *(const float4*)&as[k][ty * 8];
            *(float4*)&af[4] = *(const float4*)&as[k][ty * 8 + 4];
            *(float4*)&bf0[0] = *(const float4*)&bs[k][tx * 4];        // 2-way, free
            *(float4*)&bf1[0] = *(const float4*)&bs[k][64 + tx * 4];   // 2-way, free
#pragma unroll
            for (int i = 0; i < 8; ++i) {
#pragma unroll
                for (int j = 0; j < 4; ++j) {
                    acc[i][j]     = fmaf(af[i], bf0[j], acc[i][j]);
                    acc[i][j + 4] = fmaf(af[i], bf1[j], acc[i][j + 4]);
                }
            }
        }
    }

    float bv0[4], bv1[4];
#pragma unroll
    for (int j = 0; j < 4; ++j) {
        bv0[j] = bias[col0 + tx * 4 + j];
        bv1[j] = bias[col0 + 64 + tx * 4 + j];
    }
#pragma unroll
    for (int i = 0; i < 8; ++i) {
        const int row = row0 + ty * 8 + i;
        float4 o0, o1;
        o0.x = acc[i][0] + bv0[0]; o0.y = acc[i][1] + bv0[1];
        o0.z = acc[i][2] + bv0[2]; o0.w = acc[i][3] + bv0[3];
        o1.x = acc[i][4] + bv1[0]; o1.y = acc[i][5] + bv1[1];
        o1.z = acc[i][6] + bv1[2]; o1.w = acc[i][7] + bv1[3];
        if (relu) {
            o0.x = fmaxf(o0.x, 0.f); o0.y = fmaxf(o0.y, 0.f);
            o0.z = fmaxf(o0.z, 0.f); o0.w = fmaxf(o0.w, 0.f);
            o1.x = fmaxf(o1.x, 0.f); o1.y = fmaxf(o1.y, 0.f);
            o1.z = fmaxf(o1.z, 0.f); o1.w = fmaxf(o1.w, 0.f);
        }
        *(float4*)(C + (size_t)row * N + col0 + tx * 4) = o0;
        *(float4*)(C + (size_t)row * N + col0 + 64 + tx * 4) = o1;
    }
}

// ============================ VQ distance + argmin =========================
__global__ void cnorm_kernel(const float* __restrict__ CB, float* __restrict__ cnorm, int E)
{
    const int j = blockIdx.x;
    const float* c = CB + (size_t)j * E;
    float s = 0.f;
    for (int e = threadIdx.x; e < E; e += 64) { float v = c[e]; s += v * v; }
#pragma unroll
    for (int off = 32; off; off >>= 1) s += __shfl_down(s, off);
    if (threadIdx.x == 0) cnorm[j] = s;
}

__global__ __launch_bounds__(256, 2)
void dist_argmin(const float* __restrict__ ZE, const float* __restrict__ CB,
                 const float* __restrict__ cnorm, float* __restrict__ partv,
                 int* __restrict__ parti, int K)
{
    __shared__ float as[BKT][LDA];   // z_e rows (transposed)
    __shared__ float bs[BKT][LDB];   // codes   (transposed)
    const int tid = threadIdx.x;
    const int tx = tid & 15;
    const int ty = tid >> 4;
    const int row0 = blockIdx.y * BM;
    const int col0 = blockIdx.x * BN;

    const int ar = tid >> 2;
    const int ac = (tid & 3) << 2;
    const float* Ap0 = ZE + (size_t)(row0 + ar) * K + ac;
    const float* Ap1 = ZE + (size_t)(row0 + ar + 64) * K + ac;
    const float* Cp0 = CB + (size_t)(col0 + ar) * K + ac;
    const float* Cp1 = CB + (size_t)(col0 + ar + 64) * K + ac;

    float acc[8][8];
#pragma unroll
    for (int i = 0; i < 8; ++i)
#pragma unroll
        for (int j = 0; j < 8; ++j) acc[i][j] = 0.f;

    for (int k0 = 0; k0 < K; k0 += BKT) {
        float4 a0 = *(const float4*)(Ap0 + k0);
        float4 a1 = *(const float4*)(Ap1 + k0);
        float4 b0 = *(const float4*)(Cp0 + k0);
        float4 b1 = *(const float4*)(Cp1 + k0);
        __syncthreads();
        as[ac + 0][ar] = a0.x; as[ac + 1][ar] = a0.y;
        as[ac + 2][ar] = a0.z; as[ac + 3][ar] = a0.w;
        as[ac + 0][ar + 64] = a1.x; as[ac + 1][ar + 64] = a1.y;
        as[ac + 2][ar + 64] = a1.z; as[ac + 3][ar + 64] = a1.w;
        bs[ac + 0][ar] = b0.x; bs[ac + 1][ar] = b0.y;
        bs[ac + 2][ar] = b0.z; bs[ac + 3][ar] = b0.w;
        bs[ac + 0][ar + 64] = b1.x; bs[ac + 1][ar + 64] = b1.y;
        bs[ac + 2][ar + 64] = b1.z; bs[ac + 3][ar + 64] = b1.w;
        __syncthreads();
#pragma unroll
        for (int k = 0; k < BKT; ++k) {
            float af[8], bf0[4], bf1[4];
            *(float4*)&af[0] = *(const float4*)&as[k][ty * 8];
            *(float4*)&af[4] = *(const float4*)&as[k][ty * 8 + 4];
            *(float4*)&bf0[0] = *(const float4*)&bs[k][tx * 4];
            *(float4*)&bf1[0] = *(const float4*)&bs[k][64 + tx * 4];
#pragma unroll
            for (int i = 0; i < 8; ++i) {
#pragma unroll
                for (int j = 0; j < 4; ++j) {
                    acc[i][j]     = fmaf(af[i], bf0[j], acc[i][j]);
                    acc[i][j + 4] = fmaf(af[i], bf1[j], acc[i][j + 4]);
                }
            }
        }
    }

    float cn8[8]; int cc8[8];
#pragma unroll
    for (int j = 0; j < 4; ++j) {
        cc8[j] = col0 + tx * 4 + j;          cn8[j] = cnorm[cc8[j]];
        cc8[j + 4] = col0 + 64 + tx * 4 + j; cn8[j + 4] = cnorm[cc8[j + 4]];
    }

    float bvv[8]; int bii[8];
#pragma unroll
    for (int i = 0; i < 8; ++i) {
        bvv[i] = __builtin_inff(); bii[i] = 0;
#pragma unroll
        for (int j = 0; j < 8; ++j) {   // per-thread cols ascend with j
            float v = cn8[j] - 2.f * acc[i][j];
            if (v < bvv[i]) { bvv[i] = v; bii[i] = cc8[j]; }
        }
    }
    __syncthreads();                    // alias as/bs for the reduction
    float* rv = (float*)as;             // [128][16]
    int*   ri = (int*)bs;
#pragma unroll
    for (int i = 0; i < 8; ++i) {
        rv[(ty * 8 + i) * 16 + tx] = bvv[i];
        ri[(ty * 8 + i) * 16 + tx] = bii[i];
    }
    __syncthreads();
    if (tid < 128) {
        float best = rv[tid * 16]; int bi = ri[tid * 16];
#pragma unroll
        for (int t = 1; t < 16; ++t) {
            float v = rv[tid * 16 + t]; int ii = ri[tid * 16 + t];
            if (v < best || (v == best && ii < bi)) { best = v; bi = ii; }
        }
        const int m = row0 + tid;
        partv[(size_t)m * gridDim.x + blockIdx.x] = best;
        parti[(size_t)m * gridDim.x + blockIdx.x] = bi;
    }
}

__global__ void argmin_reduce(const float* __restrict__ partv, const int* __restrict__ parti,
                              int* __restrict__ idx, int M, int P)
{
    const int m = blockIdx.x * blockDim.x + threadIdx.x;
    if (m >= M) return;
    const float* pv = partv + (size_t)m * P;
    const int* pi = parti + (size_t)m * P;
    float best = pv[0]; int bi = pi[0];
    for (int t = 1; t < P; ++t) {
        float v = pv[t]; int ii = pi[t];
        if (v < best || (v == best && ii < bi)) { best = v; bi = ii; }
    }
    idx[m] = bi;
}

__global__ __launch_bounds__(256)
void vq_stats(const float* __restrict__ ZE, const float* __restrict__ CB,
              const int* __restrict__ idx, int* __restrict__ counts,
              float* __restrict__ vqaccum, int E)
{
    const int i = blockIdx.x;
    const int id = idx[i];
    const float* c = CB + (size_t)id * E;
    const float* z = ZE + (size_t)i * E;
    float s = 0.f;
    for (int e = threadIdx.x; e < E; e += 256) { float d = c[e] - z[e]; s += d * d; }
#pragma unroll
    for (int off = 32; off; off >>= 1) s += __shfl_down(s, off);
    __shared__ float red[4];
    const int lane = threadIdx.x & 63, w = threadIdx.x >> 6;
    if (lane == 0) red[w] = s;
    __syncthreads();
    if (threadIdx.x == 0) {
        atomicAdd(vqaccum, red[0] + red[1] + red[2] + red[3]);
        atomicAdd(counts + id, 1);
    }
}

__global__ void zero_kernel(int* __restrict__ p, int n)
{
    const int i = blockIdx.x * 256 + threadIdx.x;
    if (i < n) p[i] = 0;
}

__global__ __launch_bounds__(256)
void finalize(const int* __restrict__ counts, const float* __restrict__ vqaccum,
              float* __restrict__ tail, int NCODE, float invB, float scale)
{
    float s = 0.f;
    for (int j = threadIdx.x; j < NCODE; j += 256) {
        float p = (float)counts[j] * invB;
        s += p * logf(p + 1e-10f);
    }
#pragma unroll
    for (int off = 32; off; off >>= 1) s += __shfl_down(s, off);
    __shared__ float red[4];
    const int lane = threadIdx.x & 63, w = threadIdx.x >> 6;
    if (lane == 0) red[w] = s;
    __syncthreads();
    if (threadIdx.x == 0) {
        tail[0] = vqaccum[0] * scale;
        tail[1] = expf(-(red[0] + red[1] + red[2] + red[3]));
    }
}

// ============================ conversions ==================================
// fp32 [Kd,Nd] -> bf16 [Nd,Kd] (weight transpose for the B^T MFMA layout)
__global__ __launch_bounds__(256)
void transpose_bf16(const float* __restrict__ src, short* __restrict__ dst,
                    int Kd, int Nd)
{
    __shared__ float tile[32][33];
    const int bx = blockIdx.x * 32;   // N
    const int by = blockIdx.y * 32;   // K
    const int tx = threadIdx.x & 31, ty = threadIdx.x >> 5;
#pragma unroll
    for (int i = ty; i < 32; i += 8)
        tile[i][tx] = src[(size_t)(by + i) * Nd + bx + tx];
    __syncthreads();
#pragma unroll
    for (int i = ty; i < 32; i += 8)
        dst[(size_t)(bx + i) * Kd + by + tx] = f2bf(tile[tx][i]);
}

__global__ void convert_bf16_vec(const float* __restrict__ src, short* __restrict__ dst, int n4)
{
    const int i = blockIdx.x * 256 + threadIdx.x;
    if (i >= n4) return;
    float4 v = ((const float4*)src)[i];
    short4 o;
    o.x = f2bf(v.x); o.y = f2bf(v.y); o.z = f2bf(v.z); o.w = f2bf(v.w);
    ((short4*)dst)[i] = o;
}

// ============================ bf16 MFMA GEMM ===============================
// C[M,N] = act(A[M,K] @ BT[N,K]^T + bias) ; A bf16 (optional row gather),
// BT bf16; out fp32 (Cf) or bf16 (Cb). 128x128 tile, BK=32, 4 waves.
template<int RELU, int OUT_BF16, int GATHER>
__global__ __launch_bounds__(256)
void mfma_gemm_bt(const short* __restrict__ A, const short* __restrict__ BT,
                  const float* __restrict__ bias, float* __restrict__ Cf,
                  short* __restrict__ Cb, int M, int N, int K,
                  const int* __restrict__ rowidx)
{
    __shared__ short sA[128 * 32];   // row-major [row][k], k contiguous
    __shared__ short sB[128 * 32];
    const int t = threadIdx.x;
    const int lane = t & 63;
    const int wave = t >> 6;
    const int rh = (wave >> 1) * 64;   // wave row-half
    const int ch = (wave & 1) * 64;    // wave col-half
    const int ml = lane & 15;
    const int quad = lane >> 4;
    const int row0 = blockIdx.y * 128, col0 = blockIdx.x * 128;

    // staging: thread t loads 16B chunks; LDS dest = wave-uniform base + lane*16
    const int r = t >> 2;        // 0..63
    const int c = t & 3;         // k-chunk (8 bf16)
    int ga0 = row0 + r, ga1 = row0 + r + 64;
    if (GATHER) { ga0 = rowidx[ga0]; ga1 = rowidx[ga1]; }
    const short* pA0 = A + (size_t)ga0 * K + c * 8;
    const short* pA1 = A + (size_t)ga1 * K + c * 8;
    const short* pB0 = BT + (size_t)(col0 + r) * K + c * 8;
    const short* pB1 = BT + (size_t)(col0 + r + 64) * K + c * 8;
    short* dA0 = sA + (r * 4 + c) * 8;
    short* dA1 = sA + ((r + 64) * 4 + c) * 8;
    short* dB0 = sB + (r * 4 + c) * 8;
    short* dB1 = sB + ((r + 64) * 4 + c) * 8;

    floatx4 acc[4][4] = {};

    for (int k0 = 0; k0 < K; k0 += 32) {
        __syncthreads();
        gload16(pA0 + k0, dA0);
        gload16(pA1 + k0, dA1);
        gload16(pB0 + k0, dB0);
        gload16(pB1 + k0, dB1);
        __syncthreads();
        bf16x8 af[4], bf[4];
#pragma unroll
        for (int i = 0; i < 4; ++i)
            af[i] = *(const bf16x8*)(sA + ((rh + i * 16 + ml) * 32 + quad * 8));
#pragma unroll
        for (int j = 0; j < 4; ++j)
            bf[j] = *(const bf16x8*)(sB + ((ch + j * 16 + ml) * 32 + quad * 8));
#pragma unroll
        for (int i = 0; i < 4; ++i)
#pragma unroll
            for (int j = 0; j < 4; ++j)
                acc[i][j] = __builtin_amdgcn_mfma_f32_16x16x32_bf16(
                    af[i], bf[j], acc[i][j], 0, 0, 0);
    }

    // epilogue: C/D layout col=lane&15, row=quad*4+reg
    float bv[4];
#pragma unroll
    for (int j = 0; j < 4; ++j) bv[j] = bias[col0 + ch + j * 16 + ml];
#pragma unroll
    for (int i = 0; i < 4; ++i) {
#pragma unroll
        for (int j = 0; j < 4; ++j) {
            const int col = col0 + ch + j * 16 + ml;
#pragma unroll
            for (int reg = 0; reg < 4; ++reg) {
                const int row = row0 + rh + i * 16 + quad * 4 + reg;
                float v = acc[i][j][reg] + bv[j];
                if (RELU) v = fmaxf(v, 0.f);
                if (OUT_BF16) Cb[(size_t)row * N + col] = f2bf(v);
                else          Cf[(size_t)row * N + col] = v;
            }
        }
    }
}

// ============================ launch =======================================
extern "C" void kernel_launch(void* const* d_in, const int* in_sizes, int n_in,
                              void* d_out, int out_size, void* d_ws, size_t ws_size,
                              hipStream_t stream)
{
    const float* x      = (const float*)d_in[0];
    const float* enc_w1 = (const float*)d_in[1];
    const float* enc_b1 = (const float*)d_in[2];
    const float* enc_w2 = (const float*)d_in[3];
    const float* enc_b2 = (const float*)d_in[4];
    const float* pre_w  = (const float*)d_in[5];
    const float* pre_b  = (const float*)d_in[6];
    const float* cb     = (const float*)d_in[7];
    const float* dec_w1 = (const float*)d_in[8];
    const float* dec_b1 = (const float*)d_in[9];
    const float* dec_w2 = (const float*)d_in[10];
    const float* dec_b2 = (const float*)d_in[11];
    float* out = (float*)d_out;

    const int B = 8192, X = 4096, H = 4096, Z = 512, E = 512, NC = 8192;

    char* w = (char*)d_ws;
    float* h_buf = (float*)(w);                       // B*H f32 (dead after enc2)
    float* z_buf = (float*)(w + 134217728);           // B*Z f32
    float* ze    = (float*)(w + 150994944);           // B*E f32
    float* cn    = (float*)(w + 167772160);           // NC
    float* pv    = (float*)(w + 167804928);           // B*64
    int*   pi    = (int*)  (w + 169902080);           // B*64
    int*   idx   = (int*)  (w + 171999232);           // B
    int*   cnt   = (int*)  (w + 172032000);           // NC
    float* vqa   = (float*)(w + 172064768);           // 1
    short* cb_bf = (short*)(w + 172065024);           // NC*E bf16   (8.4 MB)
    short* dw1T  = (short*)(w + 180453632);           // [H,E] bf16  (4.2 MB)
    short* dw2T  = (short*)(w + 184647936);           // [X,H] bf16  (33.6 MB)
    short* hd_bf = (short*)(w);                       // B*H bf16, reuses h_buf region

    dim3 blk(256);

    zero_kernel<<<(NC + 1 + 255) / 256, blk, 0, stream>>>(cnt, NC + 1);

    // decoder weight conversions (independent of encoder)
    convert_bf16_vec<<<(NC * E / 4 + 255) / 256, blk, 0, stream>>>(cb, cb_bf, NC * E / 4);
    transpose_bf16<<<dim3(H / 32, E / 32), blk, 0, stream>>>(dec_w1, dw1T, E, H);
    transpose_bf16<<<dim3(X / 32, H / 32), blk, 0, stream>>>(dec_w2, dw2T, H, X);

    // encoder (fp32)
    gemm_bias_act<<<dim3(H / BN, B / BM), blk, 0, stream>>>(x, enc_w1, enc_b1, h_buf, B, H, X, 1);
    gemm_bias_act<<<dim3(Z / BN, B / BM), blk, 0, stream>>>(h_buf, enc_w2, enc_b2, z_buf, B, Z, H, 0);
    gemm_bias_act<<<dim3(E / BN, B / BM), blk, 0, stream>>>(z_buf, pre_w, pre_b, ze, B, E, Z, 0);

    // VQ (fp32, exact argmin)
    cnorm_kernel<<<NC, 64, 0, stream>>>(cb, cn, E);
    dist_argmin<<<dim3(NC / BN, B / BM), blk, 0, stream>>>(ze, cb, cn, pv, pi, E);
    argmin_reduce<<<B / 256, blk, 0, stream>>>(pv, pi, idx, B, NC / BN);
    vq_stats<<<B, blk, 0, stream>>>(ze, cb, idx, cnt, vqa, E);

    // decoder (bf16 MFMA); z_st == codebook[idx] gathered in dec1 staging.
    // NOTE: hd_bf aliases h_buf (h is dead after enc2).
    mfma_gemm_bt<1, 1, 1><<<dim3(H / 128, B / 128), blk, 0, stream>>>(
        cb_bf, dw1T, dec_b1, nullptr, hd_bf, B, H, E, idx);
    mfma_gemm_bt<0, 0, 0><<<dim3(X / 128, B / 128), blk, 0, stream>>>(
        hd_bf, dw2T, dec_b2, out, nullptr, B, X, H, nullptr);

    finalize<<<1, blk, 0, stream>>>(cnt, vqa, out + (out_size - 2), NC,
                                    1.f / (float)B, 1.25f / ((float)B * (float)E));
}